// Round 4
// baseline (320.887 us; speedup 1.0000x reference)
//
#include <hip/hip_runtime.h>
#include <math.h>

#define BATCH 4
#define NPTS  8192
#define KNN   16
#define KK    17               // top-17 incl. self (self key = j, d2=+0 exactly)
#define QPB   16               // queries per block
#define SPLITS 8               // threads per query
#define BLOCK (QPB*SPLITS)     // 128
#define RANGE (NPTS/SPLITS)    // 1024
#define SAMPLE 128             // phase-A sample per thread (union = 1024)
#define AL    8                // phase-A per-thread list size
#define CAP   30               // key-buffer rows per thread
#define CHUNK 8                // loads in flight per thread
#define NQ    (BATCH*NPTS)     // 32768
#define GRID  (NQ/QPB)         // 2048
#define JMASK 0x1FFFu
#define EMASK 0xFFFFE000u      // top 19 bits of d2 (d2 >= +0 -> uint-sortable)
#define TOTAL_EDGES (BATCH*NPTS*KNN)

// pack (x,y,z,||x||^2) for ref AND pred; zero loss accumulator + block counter
__global__ void pel_pack(const float* __restrict__ pref, const float* __restrict__ pts,
                         float4* __restrict__ p4r, float4* __restrict__ p4p,
                         float* __restrict__ acc, unsigned* __restrict__ bcnt) {
    if (blockIdx.x == 0 && threadIdx.x == 0) { acc[0] = 0.0f; bcnt[0] = 0u; }
    const int idx = blockIdx.x * blockDim.x + threadIdx.x;
    if (idx < NQ) {
        float x = pref[3*idx], y = pref[3*idx+1], z = pref[3*idx+2];
        p4r[idx] = make_float4(x, y, z, fmaf(x, x, fmaf(y, y, z*z)));
        x = pts[3*idx]; y = pts[3*idx+1]; z = pts[3*idx+2];
        p4p[idx] = make_float4(x, y, z, fmaf(x, x, fmaf(y, y, z*z)));
    }
}

__device__ __forceinline__ unsigned mkkey(const float4 p, float xi, float yi,
                                          float zi, float sqi, unsigned j) {
    const float dot = fmaf(p.x, xi, fmaf(p.y, yi, p.z * zi));
    const float d2  = fmaf(-2.0f, dot, p.w) + sqi;   // self: exact +0
    return (__float_as_uint(d2) & EMASK) | j;
}

// exact 17th-smallest key of 8 sorted runs (RL real entries each, UINT_MAX pad):
// two 4-run serial merges on lanes t<32 (t^16 partners), bitonic 17th via shfl
template<int RL>
__device__ __forceinline__ unsigned merge_tau(const unsigned (*s_key)[BLOCK], int t) {
    const int mq = t & (QPB - 1), half = t >> 4;
    unsigned m[KK];
    #pragma unroll
    for (int k = 0; k < KK; ++k) m[k] = 0xFFFFFFFFu;
    for (int s = (SPLITS/2) * half; s < (SPLITS/2) * (half + 1); ++s) {
        const int col = mq + s * QPB;
        for (int k = 0; k < RL; ++k) {
            const unsigned c = s_key[k][col];
            if (c >= m[KK-1]) break;              // runs sorted ascending
            #pragma unroll
            for (int kk = KK-1; kk >= 1; --kk) m[kk] = min(m[kk], max(m[kk-1], c));
            m[0] = min(m[0], c);
        }
    }
    unsigned tau = 0;
    #pragma unroll
    for (int k = 0; k < KK; ++k) {
        const unsigned bk = (unsigned)__shfl((int)m[KK-1-k], t ^ 16, 64);
        tau = max(tau, min(m[k], bk));
    }
    return tau;
}

__global__ __launch_bounds__(BLOCK, 4)
void pel_main(const float4* __restrict__ P4r, const float4* __restrict__ P4p,
              float* __restrict__ acc_ws, unsigned* __restrict__ bcnt,
              float* __restrict__ out)
{
    __shared__ unsigned s_key[CAP][BLOCK];   // 15.4 KB; col-major: writes 2-way-free
    __shared__ unsigned s_tau[QPB];
    __shared__ float s_part[BLOCK / 64];

    const int t  = threadIdx.x;
    const int lq = t & (QPB - 1);
    const int sp = t >> 4;
    const int q  = blockIdx.x * QPB + lq;
    const int b  = q >> 13;
    const int i  = q & (NPTS - 1);

    const float4* __restrict__ Pq = P4r + b * NPTS;
    const float4* __restrict__ Pp = P4p + b * NPTS;

    const float4 self = Pq[i];
    const float xi = self.x, yi = self.y, zi = self.z, sqi = self.w;
    const unsigned base = (unsigned)(sp * RANGE);
    const float4* __restrict__ Pb = Pq + base;

    // ---- Phase A: branchless top-AL keys over SAMPLE prefix ----
    unsigned al[AL];
    #pragma unroll
    for (int k = 0; k < AL; ++k) al[k] = 0xFFFFFFFFu;
    for (int j0 = 0; j0 < SAMPLE; j0 += CHUNK) {
        float4 c[CHUNK];
        #pragma unroll
        for (int u = 0; u < CHUNK; ++u) c[u] = Pb[j0 + u];
        #pragma unroll
        for (int u = 0; u < CHUNK; ++u) {
            const unsigned key = mkkey(c[u], xi, yi, zi, sqi, base + j0 + u);
            #pragma unroll
            for (int k = AL-1; k >= 1; --k) al[k] = min(al[k], max(al[k-1], key));
            al[0] = min(al[0], key);
        }
    }
    #pragma unroll
    for (int k = 0; k < AL; ++k) s_key[k][t] = al[k];
    __syncthreads();
    if (t < 2 * QPB) {
        const unsigned tau0 = merge_tau<AL>(s_key, t);   // >= exact 17th (sample)
        if ((t >> 4) == 0) s_tau[t & (QPB-1)] = tau0;
    }
    __syncthreads();
    unsigned tauL = s_tau[lq];

    // ---- Phase B: branchless filter scan; unconditional write + cond advance ----
    int cnt = 0;
    for (int j0 = 0; j0 < RANGE; j0 += CHUNK) {
        float4 c[CHUNK];
        #pragma unroll
        for (int u = 0; u < CHUNK; ++u) c[u] = Pb[j0 + u];
        #pragma unroll
        for (int u = 0; u < CHUNK; ++u) {
            const unsigned key = mkkey(c[u], xi, yi, zi, sqi, base + j0 + u);
            s_key[cnt][t] = key;                 // rejected keys get overwritten
            cnt += (key <= tauL) ? 1 : 0;        // max row written = 29 < CAP
        }
        if (cnt > CAP - CHUNK) {                 // rare exact compaction (<=2x ever)
            unsigned k17[KK];
            #pragma unroll
            for (int k = 0; k < KK; ++k) k17[k] = 0xFFFFFFFFu;
            for (int n = 0; n < cnt; ++n) {
                const unsigned c2 = s_key[n][t];
                #pragma unroll
                for (int k = KK-1; k >= 1; --k) k17[k] = min(k17[k], max(k17[k-1], c2));
                k17[0] = min(k17[0], c2);
            }
            const unsigned th = k17[KK-1];
            int kept = 0;
            for (int n = 0; n < cnt; ++n) {
                const unsigned c2 = s_key[n][t];
                if (c2 <= th) { s_key[kept][t] = c2; ++kept; }
            }
            cnt = kept;
            tauL = min(tauL, th);
        }
    }

    // ---- Phase C: per-thread sorted top-17 of survivors (stays in registers) ----
    unsigned c17[KK];
    #pragma unroll
    for (int k = 0; k < KK; ++k) c17[k] = 0xFFFFFFFFu;
    for (int n = 0; n < cnt; ++n) {
        const unsigned c2 = s_key[n][t];
        #pragma unroll
        for (int k = KK-1; k >= 1; --k) c17[k] = min(c17[k], max(c17[k-1], c2));
        c17[0] = min(c17[0], c2);
    }
    __syncthreads();   // all phase-B/C buffer reads done before overwrite
    #pragma unroll
    for (int k = 0; k < KK; ++k) s_key[k][t] = c17[k];
    __syncthreads();
    if (t < 2 * QPB) {
        const unsigned tauX = merge_tau<KK>(s_key, t);   // exact 17th key
        if ((t >> 4) == 0) s_tau[t & (QPB-1)] = tauX;
    }
    __syncthreads();
    const unsigned tauK = s_tau[lq];

    // ---- Phase D: full-precision |dr - dp| over the exact 17 accepted keys ----
    const float4 selfp = Pp[i];
    float accv = 0.0f;
    #pragma unroll
    for (int k = 0; k < KK; ++k) {
        if (c17[k] <= tauK) {
            const int j = (int)(c17[k] & JMASK);
            const float4 pr = Pq[j];
            const float dotr = fmaf(pr.x, xi, fmaf(pr.y, yi, pr.z * zi));
            const float d2r  = fmaxf(fmaf(-2.0f, dotr, pr.w) + sqi, 0.0f);
            const float4 pp = Pp[j];
            const float dotp = fmaf(pp.x, selfp.x, fmaf(pp.y, selfp.y, pp.z * selfp.z));
            const float d2p  = fmaxf(fmaf(-2.0f, dotp, pp.w) + selfp.w, 0.0f);
            accv += fabsf(sqrtf(d2r) - sqrtf(d2p));
        }
    }

    // ---- reduce block -> one atomic; last block finalizes (no extra launch) ----
    #pragma unroll
    for (int off = 32; off > 0; off >>= 1) accv += __shfl_down(accv, off, 64);
    if ((t & 63) == 0) s_part[t >> 6] = accv;
    __syncthreads();
    if (t == 0) {
        const float s = s_part[0] + s_part[1];
        atomicAdd(acc_ws, s);
        __threadfence();
        const unsigned old = atomicAdd(bcnt, 1u);
        if (old == GRID - 1) {
            __threadfence();
            const float total = atomicAdd(acc_ws, 0.0f);
            out[0] = total * (1.0f / (float)TOTAL_EDGES);
        }
    }
}

extern "C" void kernel_launch(void* const* d_in, const int* in_sizes, int n_in,
                              void* d_out, int out_size, void* d_ws, size_t ws_size,
                              hipStream_t stream) {
    const float* pref = (const float*)d_in[0];
    const float* pts  = (const float*)d_in[1];
    float*    acc  = (float*)d_ws;                    // ws[0]
    unsigned* bcnt = (unsigned*)d_ws + 1;             // ws[1]
    float4*   P4r  = (float4*)((char*)d_ws + 16);     // 512 KB
    float4*   P4p  = P4r + NQ;                        // 512 KB
    float*    out  = (float*)d_out;

    pel_pack<<<(NQ + 255) / 256, 256, 0, stream>>>(pref, pts, P4r, P4p, acc, bcnt);
    pel_main<<<GRID, BLOCK, 0, stream>>>(P4r, P4p, acc, bcnt, out);
}